// Round 2
// baseline (615.623 us; speedup 1.0000x reference)
//
#include <hip/hip_runtime.h>
#include <math.h>

typedef unsigned short u16;
typedef unsigned short u16x8 __attribute__((ext_vector_type(8)));
typedef __bf16 bf16x8 __attribute__((ext_vector_type(8)));
typedef float f32x4 __attribute__((ext_vector_type(4)));

typedef __attribute__((address_space(1))) const unsigned int gu32;
typedef __attribute__((address_space(3))) unsigned int su32;

#define B_ 8
#define C_ 2048
#define MID_ 512
#define N_ 2304

static __device__ __forceinline__ u16 f2bf(float f) {
  union { float f; unsigned u; } c; c.f = f;
  unsigned u = c.u;
  u += 0x7fffu + ((u >> 16) & 1u);   // round to nearest even
  return (u16)(u >> 16);
}

// ---------------- prep kernels ----------------
// Wall rows 0..511 = f_w, 512..1023 = g_w, 1024..1535 = h_w (bf16, contiguous K=2048)
__global__ __launch_bounds__(256) void prep_wall_k(
    const float* __restrict__ fw, const float* __restrict__ gw,
    const float* __restrict__ hw, u16* __restrict__ wall) {
  int idx = blockIdx.x * 256 + threadIdx.x;
  if (idx >= 1536 * 2048) return;
  int r = idx >> 11;
  float v = (r < 512) ? fw[idx] : (r < 1024) ? gw[idx - (512 << 11)] : hw[idx - (1024 << 11)];
  wall[idx] = f2bf(v);
}

__global__ __launch_bounds__(256) void prep_vw_k(const float* __restrict__ vw, u16* __restrict__ o) {
  int idx = blockIdx.x * 256 + threadIdx.x;
  if (idx < 2048 * 512) o[idx] = f2bf(vw[idx]);
}

// BN fold for f (cols 0..511) and g (cols 512..1023)
__global__ __launch_bounds__(256) void prep_sb_k(
    const float* fb, const float* fg, const float* fbe, const float* fm, const float* fv,
    const float* gb, const float* gg, const float* gbe, const float* gm, const float* gv,
    float* __restrict__ scale, float* __restrict__ bias) {
  int i = blockIdx.x * 256 + threadIdx.x;
  if (i >= 1024) return;
  if (i < 512) {
    float inv = fg[i] / sqrtf(fv[i] + 1e-5f);
    scale[i] = inv; bias[i] = fb[i] * inv + fbe[i] - fm[i] * inv;
  } else {
    int j = i - 512;
    float inv = gg[j] / sqrtf(gv[j] + 1e-5f);
    scale[i] = inv; bias[i] = gb[j] * inv + gbe[j] - gm[j] * inv;
  }
}

// x [B][C][N] f32 -> xT [B][N][C] bf16   (32x32 LDS tile transpose)
__global__ __launch_bounds__(256) void transpose_x_k(const float* __restrict__ x, u16* __restrict__ xT) {
  __shared__ float tile[32][33];
  int b = blockIdx.z;
  int n0 = blockIdx.x * 32, c0 = blockIdx.y * 32;
  int tx = threadIdx.x & 31, ty = threadIdx.x >> 5;
  const float* xb = x + (size_t)b * C_ * N_;
  u16* xTb = xT + (size_t)b * N_ * C_;
  #pragma unroll
  for (int i = 0; i < 4; ++i)
    tile[ty + i * 8][tx] = xb[(size_t)(c0 + ty + i * 8) * N_ + n0 + tx];
  __syncthreads();
  #pragma unroll
  for (int i = 0; i < 4; ++i)
    xTb[(size_t)(n0 + ty + i * 8) * C_ + c0 + tx] = f2bf(tile[tx][ty + i * 8]);
}

// ---------------- GEMM (m97 structure) ----------------
// OUT[M,N] = A[M,K] * B^T[N,K]; both operands bf16 row-major contiguous-K.
// 128x128 tile, BK=32, linear LDS, global_load_lds width-16 staging, 2 barriers/K-step.
#define EP_FG 0     // v*scale[col]+bias[col], relu, store bf16
#define EP_HB 1     // v+bias[row], store bf16
#define EP_SCORE 2  // v*fscale, store f32
#define EP_BF16 3   // store bf16
#define EP_FINAL 4  // v+bias[row]+x[row][col], store f32

template<int EPI>
__global__ __launch_bounds__(256) void gemm2_kernel(
    const u16* __restrict__ Ag, int lda, long long sA,
    const u16* __restrict__ Bg, int ldb, long long sB,
    void* __restrict__ Cg, int ldc, long long sC, int K,
    const float* __restrict__ ep_scale, const float* __restrict__ ep_bias,
    const float* __restrict__ ep_x, long long sX, float fscale)
{
  constexpr int BM = 128, BN = 128, BK = 32;
  __shared__ __align__(16) u16 Als[BM][BK];
  __shared__ __align__(16) u16 Bls[BN][BK];

  const int tid = threadIdx.x;
  const int b = blockIdx.z;
  const int m0 = blockIdx.y * BM;
  const int n0 = blockIdx.x * BN;

  const u16* Ab = Ag + (size_t)b * sA;
  const u16* Bb = Bg + (size_t)b * sB;

  f32x4 acc[4][4];
  #pragma unroll
  for (int i = 0; i < 4; ++i)
    #pragma unroll
    for (int j = 0; j < 4; ++j)
      acc[i][j] = f32x4{0.f, 0.f, 0.f, 0.f};

  const int lane = tid & 63;
  const int wv = tid >> 6;
  const int wm = (wv >> 1) * 64, wn = (wv & 1) * 64;
  const int lr = lane & 15, lg = lane >> 4;
  const int srow = lane >> 2;          // 0..15 within a 16-row 1KB chunk
  const int koff = (lane & 3) * 8;     // 0,8,16,24 (u16 elems) = 16B granularity

  for (int kt = 0; kt < K; kt += BK) {
    __syncthreads();   // previous iteration's reads done before overwrite
    // stage A and B tiles: each wave stages 32 rows of each via 2x 1KB DMA
    #pragma unroll
    for (int j = 0; j < 2; ++j) {
      const int r = wv * 32 + j * 16;                 // wave-uniform
      const u16* ga = Ab + (size_t)(m0 + r + srow) * lda + kt + koff;
      __builtin_amdgcn_global_load_lds((gu32*)ga, (su32*)&Als[r][0], 16, 0, 0);
      const u16* gb = Bb + (size_t)(n0 + r + srow) * ldb + kt + koff;
      __builtin_amdgcn_global_load_lds((gu32*)gb, (su32*)&Bls[r][0], 16, 0, 0);
    }
    __syncthreads();   // compiler drains vmcnt(0) here -> LDS ready
    // each wave: 64x64 quadrant = 4x4 fragments of 16x16x32
    bf16x8 af[4], bfv[4];
    #pragma unroll
    for (int m = 0; m < 4; ++m) af[m] = *(const bf16x8*)&Als[wm + m * 16 + lr][lg * 8];
    #pragma unroll
    for (int n = 0; n < 4; ++n) bfv[n] = *(const bf16x8*)&Bls[wn + n * 16 + lr][lg * 8];
    #pragma unroll
    for (int m = 0; m < 4; ++m)
      #pragma unroll
      for (int n = 0; n < 4; ++n)
        acc[m][n] = __builtin_amdgcn_mfma_f32_16x16x32_bf16(af[m], bfv[n], acc[m][n], 0, 0, 0);
  }

  // epilogue: D row = 4*lg + r, col = lr within each 16x16 fragment
  u16*   C16 = (u16*)Cg + (size_t)b * sC;
  float* C32 = (float*)Cg + (size_t)b * sC;
  const float* xb = (EPI == EP_FINAL) ? (ep_x + (size_t)b * sX) : nullptr;
  #pragma unroll
  for (int m = 0; m < 4; ++m) {
    #pragma unroll
    for (int n = 0; n < 4; ++n) {
      #pragma unroll
      for (int r = 0; r < 4; ++r) {
        int row = m0 + wm + m * 16 + lg * 4 + r;
        int col = n0 + wn + n * 16 + lr;
        float v = acc[m][n][r];
        if constexpr (EPI == EP_FG) {
          v = v * ep_scale[col] + ep_bias[col];
          v = fmaxf(v, 0.f);
          C16[(size_t)row * ldc + col] = f2bf(v);
        } else if constexpr (EPI == EP_HB) {
          C16[(size_t)row * ldc + col] = f2bf(v + ep_bias[row]);
        } else if constexpr (EPI == EP_SCORE) {
          C32[(size_t)row * ldc + col] = v * fscale;
        } else if constexpr (EPI == EP_BF16) {
          C16[(size_t)row * ldc + col] = f2bf(v);
        } else {
          v += ep_bias[row] + xb[(size_t)row * ldc + col];
          C32[(size_t)row * ldc + col] = v;
        }
      }
    }
  }
}

// ---------------- softmax (rows of 2304, fp32 in place + bf16 copy) ----------------
__global__ __launch_bounds__(256) void softmax_k(float* __restrict__ attn, u16* __restrict__ P) {
  float* r = attn + (size_t)blockIdx.x * N_;
  u16* pr = P + (size_t)blockIdx.x * N_;
  const int tid = threadIdx.x;
  float v[9];
  float mx = -3.0e38f;
  #pragma unroll
  for (int j = 0; j < 9; ++j) { v[j] = r[tid + j * 256]; mx = fmaxf(mx, v[j]); }
  #pragma unroll
  for (int o = 32; o; o >>= 1) mx = fmaxf(mx, __shfl_xor(mx, o));
  __shared__ float red[4], red2[4];
  if ((tid & 63) == 0) red[tid >> 6] = mx;
  __syncthreads();
  mx = fmaxf(fmaxf(red[0], red[1]), fmaxf(red[2], red[3]));
  float s = 0.f;
  #pragma unroll
  for (int j = 0; j < 9; ++j) { v[j] = __expf(v[j] - mx); s += v[j]; }
  #pragma unroll
  for (int o = 32; o; o >>= 1) s += __shfl_xor(s, o);
  if ((tid & 63) == 0) red2[tid >> 6] = s;
  __syncthreads();
  s = red2[0] + red2[1] + red2[2] + red2[3];
  float inv = 1.0f / s;
  #pragma unroll
  for (int j = 0; j < 9; ++j) {
    float o = v[j] * inv;
    r[tid + j * 256] = o;
    pr[tid + j * 256] = f2bf(o);
  }
}

// ---------------- launch ----------------
extern "C" void kernel_launch(void* const* d_in, const int* in_sizes, int n_in,
                              void* d_out, int out_size, void* d_ws, size_t ws_size,
                              hipStream_t stream) {
  const float* x    = (const float*)d_in[0];
  const float* f_w  = (const float*)d_in[1];
  const float* f_b  = (const float*)d_in[2];
  const float* f_ga = (const float*)d_in[3];
  const float* f_be = (const float*)d_in[4];
  const float* f_me = (const float*)d_in[5];
  const float* f_va = (const float*)d_in[6];
  const float* g_w  = (const float*)d_in[7];
  const float* g_b  = (const float*)d_in[8];
  const float* g_ga = (const float*)d_in[9];
  const float* g_be = (const float*)d_in[10];
  const float* g_me = (const float*)d_in[11];
  const float* g_va = (const float*)d_in[12];
  const float* h_w  = (const float*)d_in[13];
  const float* h_b  = (const float*)d_in[14];
  const float* v_w  = (const float*)d_in[15];
  const float* v_b  = (const float*)d_in[16];

  float* out0 = (float*)d_out;
  float* attn = out0 + (size_t)B_ * C_ * N_;   // second output region

  // workspace carve (~160 MB; P reuses dead xT+fghT region after G2)
  char* p = (char*)d_ws;
  u16* xT   = (u16*)p; p += (size_t)B_ * N_ * C_ * 2;       // 75.5 MB (dead after G1h)
  u16* fghT = (u16*)p; p += (size_t)B_ * N_ * 1024 * 2;     // 37.7 MB (dead after G2)
  u16* hx   = (u16*)p; p += (size_t)B_ * MID_ * N_ * 2;     // 18.9 MB
  u16* ZT   = (u16*)p; p += (size_t)B_ * N_ * MID_ * 2;     // 18.9 MB
  u16* Wall = (u16*)p; p += (size_t)1536 * C_ * 2;          // 6.3 MB
  u16* vwb  = (u16*)p; p += (size_t)C_ * MID_ * 2;          // 2.1 MB
  float* sc = (float*)p; p += 1024 * 4;
  float* bi = (float*)p; p += 1024 * 4;
  u16* P = xT;                                              // 85 MB, overlaps xT+fghT

  prep_wall_k<<<(1536 * 2048 + 255) / 256, 256, 0, stream>>>(f_w, g_w, h_w, Wall);
  prep_vw_k<<<(2048 * 512 + 255) / 256, 256, 0, stream>>>(v_w, vwb);
  prep_sb_k<<<4, 256, 0, stream>>>(f_b, f_ga, f_be, f_me, f_va,
                                   g_b, g_ga, g_be, g_me, g_va, sc, bi);
  transpose_x_k<<<dim3(N_ / 32, C_ / 32, B_), 256, 0, stream>>>(x, xT);

  // G1fg: fghT[n][c'] = xT[n][:] . Wfg[c'][:]  (M=2304,N=1024,K=2048) + BN/ReLU -> bf16
  gemm2_kernel<EP_FG><<<dim3(1024 / 128, N_ / 128, B_), 256, 0, stream>>>(
      xT, C_, (long long)N_ * C_, Wall, C_, 0,
      fghT, 1024, (long long)N_ * 1024, C_, sc, bi, nullptr, 0, 0.f);

  // G1h: hx[c][n] = Wh[c][:] . xT[n][:]  (M=512,N=2304,K=2048) + h_b -> bf16
  gemm2_kernel<EP_HB><<<dim3(N_ / 128, MID_ / 128, B_), 256, 0, stream>>>(
      Wall + (size_t)1024 * C_, C_, 0, xT, C_, (long long)N_ * C_,
      hx, N_, (long long)MID_ * N_, C_, nullptr, h_b, nullptr, 0, 0.f);

  // G2: scores[n][m] = fT[n][:] . gT[m][:] * mid^-0.5  (M=N=2304,K=512) -> f32 attn
  const float fscale = 0.044194173824159216f;  // 512^-0.5
  gemm2_kernel<EP_SCORE><<<dim3(N_ / 128, N_ / 128, B_), 256, 0, stream>>>(
      fghT, 1024, (long long)N_ * 1024, fghT + 512, 1024, (long long)N_ * 1024,
      attn, N_, (long long)N_ * N_, MID_, nullptr, nullptr, nullptr, 0, fscale);

  softmax_k<<<B_ * N_, 256, 0, stream>>>(attn, P);

  // G3: ZT[n][c] = P[n][:] . hx[c][:]  (M=2304,N=512,K=2304) -> bf16
  gemm2_kernel<EP_BF16><<<dim3(MID_ / 128, N_ / 128, B_), 256, 0, stream>>>(
      P, N_, (long long)N_ * N_, hx, N_, (long long)MID_ * N_,
      ZT, MID_, (long long)N_ * MID_, N_, nullptr, nullptr, nullptr, 0, 0.f);

  // G5: out[o][n] = vw[o][:] . ZT[n][:] + v_b[o] + x[o][n]  (M=2048,N=2304,K=512) -> f32
  gemm2_kernel<EP_FINAL><<<dim3(N_ / 128, C_ / 128, B_), 256, 0, stream>>>(
      vwb, MID_, 0, ZT, MID_, (long long)N_ * MID_,
      out0, N_, (long long)C_ * N_, MID_, nullptr, v_b, x, (long long)C_ * N_, 0.f);
}

// Round 3
// 562.341 us; speedup vs baseline: 1.0948x; 1.0948x over previous
//
#include <hip/hip_runtime.h>
#include <math.h>

typedef unsigned short u16;
typedef unsigned short u16x8 __attribute__((ext_vector_type(8)));
typedef __bf16 bf16x8 __attribute__((ext_vector_type(8)));
typedef float f32x4 __attribute__((ext_vector_type(4)));

typedef __attribute__((address_space(1))) const unsigned int gu32;
typedef __attribute__((address_space(3))) unsigned int su32;

#define B_ 8
#define C_ 2048
#define MID_ 512
#define N_ 2304

static __device__ __forceinline__ u16 f2bf(float f) {
  union { float f; unsigned u; } c; c.f = f;
  unsigned u = c.u;
  u += 0x7fffu + ((u >> 16) & 1u);   // round to nearest even
  return (u16)(u >> 16);
}

// ---------------- prep kernels ----------------
// Wall rows 0..511 = f_w, 512..1023 = g_w, 1024..1535 = h_w (bf16, contiguous K=2048)
__global__ __launch_bounds__(256) void prep_wall_k(
    const float* __restrict__ fw, const float* __restrict__ gw,
    const float* __restrict__ hw, u16* __restrict__ wall) {
  int idx = blockIdx.x * 256 + threadIdx.x;
  if (idx >= 1536 * 2048) return;
  int r = idx >> 11;
  float v = (r < 512) ? fw[idx] : (r < 1024) ? gw[idx - (512 << 11)] : hw[idx - (1024 << 11)];
  wall[idx] = f2bf(v);
}

__global__ __launch_bounds__(256) void prep_vw_k(const float* __restrict__ vw, u16* __restrict__ o) {
  int idx = blockIdx.x * 256 + threadIdx.x;
  if (idx < 2048 * 512) o[idx] = f2bf(vw[idx]);
}

// BN fold for f (cols 0..511) and g (cols 512..1023)
__global__ __launch_bounds__(256) void prep_sb_k(
    const float* fb, const float* fg, const float* fbe, const float* fm, const float* fv,
    const float* gb, const float* gg, const float* gbe, const float* gm, const float* gv,
    float* __restrict__ scale, float* __restrict__ bias) {
  int i = blockIdx.x * 256 + threadIdx.x;
  if (i >= 1024) return;
  if (i < 512) {
    float inv = fg[i] / sqrtf(fv[i] + 1e-5f);
    scale[i] = inv; bias[i] = fb[i] * inv + fbe[i] - fm[i] * inv;
  } else {
    int j = i - 512;
    float inv = gg[j] / sqrtf(gv[j] + 1e-5f);
    scale[i] = inv; bias[i] = gb[j] * inv + gbe[j] - gm[j] * inv;
  }
}

// x [B][C][N] f32 -> xT [B][N][C] bf16   (32x32 LDS tile transpose)
__global__ __launch_bounds__(256) void transpose_x_k(const float* __restrict__ x, u16* __restrict__ xT) {
  __shared__ float tile[32][33];
  int b = blockIdx.z;
  int n0 = blockIdx.x * 32, c0 = blockIdx.y * 32;
  int tx = threadIdx.x & 31, ty = threadIdx.x >> 5;
  const float* xb = x + (size_t)b * C_ * N_;
  u16* xTb = xT + (size_t)b * N_ * C_;
  #pragma unroll
  for (int i = 0; i < 4; ++i)
    tile[ty + i * 8][tx] = xb[(size_t)(c0 + ty + i * 8) * N_ + n0 + tx];
  __syncthreads();
  #pragma unroll
  for (int i = 0; i < 4; ++i)
    xTb[(size_t)(n0 + ty + i * 8) * C_ + c0 + tx] = f2bf(tile[tx][ty + i * 8]);
}

// ---------------- GEMM: 256x256 tile, BK=32, 4-slot LDS ring, counted vmcnt ----------------
// OUT[M,N] = A[M,K] * B^T[N,K]; both operands bf16 row-major contiguous-K.
// 512 threads = 8 waves (2M x 4N); per-wave output 128x64 (8x4 fragments of 16x16).
// LDS ring: 4 slots x (A 16KB + B 16KB) = 128KB dynamic; stage tile kt+3 each iter.
// Ledger: iter kt waits vmcnt(8) (drains slot kt's 4 loads of 12 outstanding), barrier,
// ds_read slot kt, stage slot (kt+3)&3 (== slot kt-1, reads completed before this barrier
// via trailing lgkmcnt(0)), MFMA. Steady state never drains vmcnt (T4).
// T2 swizzle: LDS cell (row, chunk) holds global chunk (chunk ^ ((row>>1)&3));
// applied on the global source at stage time and on the ds_read address (XOR involution).
#define EP_FG 0     // v*scale[col]+bias[col], relu, store bf16
#define EP_HB 1     // v+bias[row], store bf16
#define EP_SCORE 2  // v*fscale, store f32
#define EP_BF16 3   // store bf16
#define EP_FINAL 4  // v+bias[row]+x[row][col], store f32

template<int EPI>
__global__ __launch_bounds__(512, 2) void gemm3_kernel(
    const u16* __restrict__ Ag, int lda, long long sA,
    const u16* __restrict__ Bg, int ldb, long long sB,
    void* __restrict__ Cg, int ldc, long long sC, int K,
    const float* __restrict__ ep_scale, const float* __restrict__ ep_bias,
    const float* __restrict__ ep_x, long long sX, float fscale)
{
  extern __shared__ __align__(16) u16 smem[];
  u16* As = smem;                    // [4][256][32]
  u16* Bs = smem + 4 * 256 * 32;     // [4][256][32]

  const int tid = threadIdx.x;
  const int lane = tid & 63;
  const int wv = tid >> 6;           // 0..7
  const int b = blockIdx.z;
  const int m0 = blockIdx.y * 256;
  const int n0 = blockIdx.x * 256;
  const int wm = (wv >> 2) * 128;    // 0 or 128
  const int wn = (wv & 3) * 64;      // 0,64,128,192
  const int lr = lane & 15, lg = lane >> 4;

  const u16* Ab = Ag + (size_t)b * sA;
  const u16* Bb = Bg + (size_t)b * sB;

  const int nk = K >> 5;             // K-tiles of 32

  // staging coords: lane writes LDS (row rb+lane/4, chunk lane&3) linearly
  const int srow = lane >> 2;
  const int sch  = lane & 3;

  // fragment-read swizzle: ((wm+mf*16+lr)>>1)&3 is mf-invariant
  const int cA = ((lg ^ (((wm + lr) >> 1) & 3)) * 8);
  const int cB = ((lg ^ (((wn + lr) >> 1) & 3)) * 8);

  f32x4 acc[8][4];
  #pragma unroll
  for (int i = 0; i < 8; ++i)
    #pragma unroll
    for (int j = 0; j < 4; ++j)
      acc[i][j] = f32x4{0.f, 0.f, 0.f, 0.f};

  auto STAGE = [&](int slot, int kt) {
    #pragma unroll
    for (int j = 0; j < 2; ++j) {
      const int rb = j * 128 + wv * 16;          // wave-uniform row base
      const int arow = rb + srow;
      // A
      {
        const int gch = sch ^ ((arow >> 1) & 3); // inverse swizzle on global source
        const u16* ga = Ab + (size_t)(m0 + arow) * lda + kt * 32 + gch * 8;
        __builtin_amdgcn_global_load_lds((gu32*)ga, (su32*)(As + (slot * 256 + rb) * 32), 16, 0, 0);
      }
      // B
      {
        const int gch = sch ^ ((arow >> 1) & 3);
        const u16* gb = Bb + (size_t)(n0 + arow) * ldb + kt * 32 + gch * 8;
        __builtin_amdgcn_global_load_lds((gu32*)gb, (su32*)(Bs + (slot * 256 + rb) * 32), 16, 0, 0);
      }
    }
  };

  STAGE(0, 0); STAGE(1, 1); STAGE(2, 2);   // depth-3 prologue (12 loads/wave in flight)

  for (int kt = 0; kt < nk; ++kt) {
    const int slot = kt & 3;
    if (kt < nk - 2)        asm volatile("s_waitcnt vmcnt(8)" ::: "memory");
    else if (kt == nk - 2)  asm volatile("s_waitcnt vmcnt(4)" ::: "memory");
    else                    asm volatile("s_waitcnt vmcnt(0)" ::: "memory");
    __builtin_amdgcn_s_barrier();

    const u16* Asl = As + slot * (256 * 32);
    const u16* Bsl = Bs + slot * (256 * 32);
    bf16x8 af[8], bf[4];
    #pragma unroll
    for (int mf = 0; mf < 8; ++mf)
      af[mf] = *(const bf16x8*)(Asl + (wm + mf * 16 + lr) * 32 + cA);
    #pragma unroll
    for (int nf = 0; nf < 4; ++nf)
      bf[nf] = *(const bf16x8*)(Bsl + (wn + nf * 16 + lr) * 32 + cB);

    if (kt + 3 < nk) STAGE((kt + 3) & 3, kt + 3);   // issue-early prefetch (T14)

    __builtin_amdgcn_s_setprio(1);
    #pragma unroll
    for (int mf = 0; mf < 8; ++mf)
      #pragma unroll
      for (int nf = 0; nf < 4; ++nf)
        acc[mf][nf] = __builtin_amdgcn_mfma_f32_16x16x32_bf16(af[mf], bf[nf], acc[mf][nf], 0, 0, 0);
    __builtin_amdgcn_s_setprio(0);
    // force all ds_reads of this slot complete before next barrier (write-after-read fence)
    asm volatile("s_waitcnt lgkmcnt(0)" ::: "memory");
  }

  // epilogue: D row = 4*lg + r, col = lr within each 16x16 fragment
  u16*   C16 = (u16*)Cg + (size_t)b * sC;
  float* C32 = (float*)Cg + (size_t)b * sC;
  const float* xb = (EPI == EP_FINAL) ? (ep_x + (size_t)b * sX) : nullptr;
  #pragma unroll
  for (int mf = 0; mf < 8; ++mf) {
    #pragma unroll
    for (int nf = 0; nf < 4; ++nf) {
      #pragma unroll
      for (int r = 0; r < 4; ++r) {
        int row = m0 + wm + mf * 16 + lg * 4 + r;
        int col = n0 + wn + nf * 16 + lr;
        float v = acc[mf][nf][r];
        if constexpr (EPI == EP_FG) {
          v = v * ep_scale[col] + ep_bias[col];
          v = fmaxf(v, 0.f);
          C16[(size_t)row * ldc + col] = f2bf(v);
        } else if constexpr (EPI == EP_HB) {
          C16[(size_t)row * ldc + col] = f2bf(v + ep_bias[row]);
        } else if constexpr (EPI == EP_SCORE) {
          C32[(size_t)row * ldc + col] = v * fscale;
        } else if constexpr (EPI == EP_BF16) {
          C16[(size_t)row * ldc + col] = f2bf(v);
        } else {
          v += ep_bias[row] + xb[(size_t)row * ldc + col];
          C32[(size_t)row * ldc + col] = v;
        }
      }
    }
  }
}

// ---------------- softmax (rows of 2304, fp32 in place + bf16 copy) ----------------
__global__ __launch_bounds__(256) void softmax_k(float* __restrict__ attn, u16* __restrict__ P) {
  float* r = attn + (size_t)blockIdx.x * N_;
  u16* pr = P + (size_t)blockIdx.x * N_;
  const int tid = threadIdx.x;
  float v[9];
  float mx = -3.0e38f;
  #pragma unroll
  for (int j = 0; j < 9; ++j) { v[j] = r[tid + j * 256]; mx = fmaxf(mx, v[j]); }
  #pragma unroll
  for (int o = 32; o; o >>= 1) mx = fmaxf(mx, __shfl_xor(mx, o));
  __shared__ float red[4], red2[4];
  if ((tid & 63) == 0) red[tid >> 6] = mx;
  __syncthreads();
  mx = fmaxf(fmaxf(red[0], red[1]), fmaxf(red[2], red[3]));
  float s = 0.f;
  #pragma unroll
  for (int j = 0; j < 9; ++j) { v[j] = __expf(v[j] - mx); s += v[j]; }
  #pragma unroll
  for (int o = 32; o; o >>= 1) s += __shfl_xor(s, o);
  if ((tid & 63) == 0) red2[tid >> 6] = s;
  __syncthreads();
  s = red2[0] + red2[1] + red2[2] + red2[3];
  float inv = 1.0f / s;
  #pragma unroll
  for (int j = 0; j < 9; ++j) {
    float o = v[j] * inv;
    r[tid + j * 256] = o;
    pr[tid + j * 256] = f2bf(o);
  }
}

// ---------------- launch ----------------
extern "C" void kernel_launch(void* const* d_in, const int* in_sizes, int n_in,
                              void* d_out, int out_size, void* d_ws, size_t ws_size,
                              hipStream_t stream) {
  const float* x    = (const float*)d_in[0];
  const float* f_w  = (const float*)d_in[1];
  const float* f_b  = (const float*)d_in[2];
  const float* f_ga = (const float*)d_in[3];
  const float* f_be = (const float*)d_in[4];
  const float* f_me = (const float*)d_in[5];
  const float* f_va = (const float*)d_in[6];
  const float* g_w  = (const float*)d_in[7];
  const float* g_b  = (const float*)d_in[8];
  const float* g_ga = (const float*)d_in[9];
  const float* g_be = (const float*)d_in[10];
  const float* g_me = (const float*)d_in[11];
  const float* g_va = (const float*)d_in[12];
  const float* h_w  = (const float*)d_in[13];
  const float* h_b  = (const float*)d_in[14];
  const float* v_w  = (const float*)d_in[15];
  const float* v_b  = (const float*)d_in[16];

  float* out0 = (float*)d_out;
  float* attn = out0 + (size_t)B_ * C_ * N_;   // second output region

  // workspace carve (~160 MB; P reuses dead xT region after softmax)
  char* p = (char*)d_ws;
  u16* xT   = (u16*)p; p += (size_t)B_ * N_ * C_ * 2;       // 75.5 MB (dead after G1h)
  u16* fghT = (u16*)p; p += (size_t)B_ * N_ * 1024 * 2;     // 37.7 MB (dead after G2)
  u16* hx   = (u16*)p; p += (size_t)B_ * MID_ * N_ * 2;     // 18.9 MB
  u16* ZT   = (u16*)p; p += (size_t)B_ * N_ * MID_ * 2;     // 18.9 MB
  u16* Wall = (u16*)p; p += (size_t)1536 * C_ * 2;          // 6.3 MB
  u16* vwb  = (u16*)p; p += (size_t)C_ * MID_ * 2;          // 2.1 MB
  float* sc = (float*)p; p += 1024 * 4;
  float* bi = (float*)p; p += 1024 * 4;
  u16* P = xT;                                              // 85 MB, overlaps xT+fghT

  // allow 128KB dynamic LDS on the gemm instantiations (idempotent, capture-safe)
  hipFuncSetAttribute((const void*)gemm3_kernel<EP_FG>,    hipFuncAttributeMaxDynamicSharedMemorySize, 131072);
  hipFuncSetAttribute((const void*)gemm3_kernel<EP_HB>,    hipFuncAttributeMaxDynamicSharedMemorySize, 131072);
  hipFuncSetAttribute((const void*)gemm3_kernel<EP_SCORE>, hipFuncAttributeMaxDynamicSharedMemorySize, 131072);
  hipFuncSetAttribute((const void*)gemm3_kernel<EP_BF16>,  hipFuncAttributeMaxDynamicSharedMemorySize, 131072);
  hipFuncSetAttribute((const void*)gemm3_kernel<EP_FINAL>, hipFuncAttributeMaxDynamicSharedMemorySize, 131072);

  prep_wall_k<<<(1536 * 2048 + 255) / 256, 256, 0, stream>>>(f_w, g_w, h_w, Wall);
  prep_vw_k<<<(2048 * 512 + 255) / 256, 256, 0, stream>>>(v_w, vwb);
  prep_sb_k<<<4, 256, 0, stream>>>(f_b, f_ga, f_be, f_me, f_va,
                                   g_b, g_ga, g_be, g_me, g_va, sc, bi);
  transpose_x_k<<<dim3(N_ / 32, C_ / 32, B_), 256, 0, stream>>>(x, xT);

  // G1fg: fghT[n][c'] = xT[n][:] . Wfg[c'][:]  (M=2304,N=1024,K=2048) + BN/ReLU -> bf16
  gemm3_kernel<EP_FG><<<dim3(1024 / 256, N_ / 256, B_), 512, 131072, stream>>>(
      xT, C_, (long long)N_ * C_, Wall, C_, 0,
      fghT, 1024, (long long)N_ * 1024, C_, sc, bi, nullptr, 0, 0.f);

  // G1h: hx[c][n] = Wh[c][:] . xT[n][:]  (M=512,N=2304,K=2048) + h_b -> bf16
  gemm3_kernel<EP_HB><<<dim3(N_ / 256, MID_ / 256, B_), 512, 131072, stream>>>(
      Wall + (size_t)1024 * C_, C_, 0, xT, C_, (long long)N_ * C_,
      hx, N_, (long long)MID_ * N_, C_, nullptr, h_b, nullptr, 0, 0.f);

  // G2: scores[n][m] = fT[n][:] . gT[m][:] * mid^-0.5  (M=N=2304,K=512) -> f32 attn
  const float fscale = 0.044194173824159216f;  // 512^-0.5
  gemm3_kernel<EP_SCORE><<<dim3(N_ / 256, N_ / 256, B_), 512, 131072, stream>>>(
      fghT, 1024, (long long)N_ * 1024, fghT + 512, 1024, (long long)N_ * 1024,
      attn, N_, (long long)N_ * N_, MID_, nullptr, nullptr, nullptr, 0, fscale);

  softmax_k<<<B_ * N_, 256, 0, stream>>>(attn, P);

  // G3: ZT[n][c] = P[n][:] . hx[c][:]  (M=2304,N=512,K=2304) -> bf16
  gemm3_kernel<EP_BF16><<<dim3(MID_ / 256, N_ / 256, B_), 512, 131072, stream>>>(
      P, N_, (long long)N_ * N_, hx, N_, (long long)MID_ * N_,
      ZT, MID_, (long long)N_ * MID_, N_, nullptr, nullptr, nullptr, 0, 0.f);

  // G5: out[o][n] = vw[o][:] . ZT[n][:] + v_b[o] + x[o][n]  (M=2048,N=2304,K=512) -> f32
  gemm3_kernel<EP_FINAL><<<dim3(N_ / 256, C_ / 256, B_), 512, 131072, stream>>>(
      vwb, MID_, 0, ZT, MID_, (long long)N_ * MID_,
      out0, N_, (long long)C_ * N_, MID_, nullptr, v_b, x, (long long)C_ * N_, 0.f);
}

// Round 4
// 518.839 us; speedup vs baseline: 1.1865x; 1.0838x over previous
//
#include <hip/hip_runtime.h>
#include <math.h>

typedef unsigned short u16;
typedef unsigned short u16x4 __attribute__((ext_vector_type(4)));
typedef unsigned short u16x8 __attribute__((ext_vector_type(8)));
typedef __bf16 bf16x8 __attribute__((ext_vector_type(8)));
typedef float f32x4 __attribute__((ext_vector_type(4)));

typedef __attribute__((address_space(1))) const unsigned int gu32;
typedef __attribute__((address_space(3))) unsigned int su32;

#define B_ 8
#define C_ 2048
#define MID_ 512
#define N_ 2304

static __device__ __forceinline__ u16 f2bf(float f) {
  union { float f; unsigned u; } c; c.f = f;
  unsigned u = c.u;
  u += 0x7fffu + ((u >> 16) & 1u);   // round to nearest even
  return (u16)(u >> 16);
}

// ---------------- prep kernels ----------------
// Wall rows 0..511 = f_w, 512..1023 = g_w, 1024..1535 = h_w (bf16, contiguous K=2048)
__global__ __launch_bounds__(256) void prep_wall_k(
    const float* __restrict__ fw, const float* __restrict__ gw,
    const float* __restrict__ hw, u16* __restrict__ wall) {
  int idx = blockIdx.x * 256 + threadIdx.x;
  if (idx >= 1536 * 2048) return;
  int r = idx >> 11;
  float v = (r < 512) ? fw[idx] : (r < 1024) ? gw[idx - (512 << 11)] : hw[idx - (1024 << 11)];
  wall[idx] = f2bf(v);
}

__global__ __launch_bounds__(256) void prep_vw_k(const float* __restrict__ vw, u16* __restrict__ o) {
  int idx = blockIdx.x * 256 + threadIdx.x;
  if (idx < 2048 * 512) o[idx] = f2bf(vw[idx]);
}

// BN fold: cols 0..511 f (relu), 512..1023 g (relu), 1024..1535 h (scale=1, bias=h_b)
__global__ __launch_bounds__(256) void prep_sb_k(
    const float* fb, const float* fg, const float* fbe, const float* fm, const float* fv,
    const float* gb, const float* gg, const float* gbe, const float* gm, const float* gv,
    const float* hb, float* __restrict__ scale, float* __restrict__ bias) {
  int i = blockIdx.x * 256 + threadIdx.x;
  if (i >= 1536) return;
  if (i < 512) {
    float inv = fg[i] / sqrtf(fv[i] + 1e-5f);
    scale[i] = inv; bias[i] = fb[i] * inv + fbe[i] - fm[i] * inv;
  } else if (i < 1024) {
    int j = i - 512;
    float inv = gg[j] / sqrtf(gv[j] + 1e-5f);
    scale[i] = inv; bias[i] = gb[j] * inv + gbe[j] - gm[j] * inv;
  } else {
    scale[i] = 1.0f; bias[i] = hb[i - 1024];
  }
}

// x [B][C][N] f32 -> xT [B][N][C] bf16   (64x64 tile, float4 loads, 16B stores)
__global__ __launch_bounds__(256) void transpose_x_k(const float* __restrict__ x, u16* __restrict__ xT) {
  __shared__ float tile[64][68];
  const int b = blockIdx.z;
  const int n0 = blockIdx.x * 64, c0 = blockIdx.y * 64;
  const float* xb = x + (size_t)b * C_ * N_;
  u16* xTb = xT + (size_t)b * N_ * C_;
  const int r = threadIdx.x >> 2, q = threadIdx.x & 3;
  #pragma unroll
  for (int j = 0; j < 4; ++j) {
    float4 v = *(const float4*)&xb[(size_t)(c0 + r) * N_ + n0 + (q + 4 * j) * 4];
    *(float4*)&tile[r][(q + 4 * j) * 4] = v;
  }
  __syncthreads();
  #pragma unroll
  for (int g = 0; g < 2; ++g) {
    const int cl = (q * 2 + g) * 8;
    u16x8 w;
    #pragma unroll
    for (int e = 0; e < 8; ++e) w[e] = f2bf(tile[cl + e][r]);
    *(u16x8*)&xTb[(size_t)(n0 + r) * C_ + c0 + cl] = w;
  }
}

// fghT h-columns [B][N][1024+c] -> hx [B][512][N]  (bf16 32x32 tile transpose)
__global__ __launch_bounds__(256) void transpose_h_k(const u16* __restrict__ fghT, u16* __restrict__ hx) {
  __shared__ u16 tile[32][33];
  const int b = blockIdx.z;
  const int n0 = blockIdx.x * 32, c0 = blockIdx.y * 32;
  const u16* src = fghT + (size_t)b * N_ * 1536;
  u16* dst = hx + (size_t)b * MID_ * N_;
  const int tx = threadIdx.x & 31, ty = threadIdx.x >> 5;
  #pragma unroll
  for (int i = 0; i < 4; ++i)
    tile[ty + i * 8][tx] = src[(size_t)(n0 + ty + i * 8) * 1536 + 1024 + c0 + tx];
  __syncthreads();
  #pragma unroll
  for (int i = 0; i < 4; ++i)
    dst[(size_t)(c0 + ty + i * 8) * N_ + n0 + tx] = tile[tx][ty + i * 8];
}

// ---------------- GEMM: 256x256 tile, BK=32, 4-slot LDS ring, counted vmcnt ----------------
// OUT[M,N] = A[M,K] * B^T[N,K]; both operands bf16 row-major contiguous-K.
// 512 threads = 8 waves (2M x 4N); per-wave output 128x64 (8x4 fragments of 16x16).
#define EP_FG 0     // v*scale[col]+bias[col], relu if col<1024, store bf16
#define EP_SCORE 2  // v*fscale, store f32
#define EP_BF16 3   // store bf16
#define EP_FINAL 4  // v+bias[row]+x[row][col], store f32

template<int EPI>
__global__ __launch_bounds__(512, 2) void gemm3_kernel(
    const u16* __restrict__ Ag, int lda, long long sA,
    const u16* __restrict__ Bg, int ldb, long long sB,
    void* __restrict__ Cg, int ldc, long long sC, int K,
    const float* __restrict__ ep_scale, const float* __restrict__ ep_bias,
    const float* __restrict__ ep_x, long long sX, float fscale)
{
  extern __shared__ __align__(16) u16 smem[];
  u16* As = smem;                    // [4][256][32]
  u16* Bs = smem + 4 * 256 * 32;     // [4][256][32]

  const int tid = threadIdx.x;
  const int lane = tid & 63;
  const int wv = tid >> 6;           // 0..7
  const int b = blockIdx.z;
  const int m0 = blockIdx.y * 256;
  const int n0 = blockIdx.x * 256;
  const int wm = (wv >> 2) * 128;    // 0 or 128
  const int wn = (wv & 3) * 64;      // 0,64,128,192
  const int lr = lane & 15, lg = lane >> 4;

  const u16* Ab = Ag + (size_t)b * sA;
  const u16* Bb = Bg + (size_t)b * sB;

  const int nk = K >> 5;             // K-tiles of 32

  const int srow = lane >> 2;
  const int sch  = lane & 3;

  const int cA = ((lg ^ (((wm + lr) >> 1) & 3)) * 8);
  const int cB = ((lg ^ (((wn + lr) >> 1) & 3)) * 8);

  f32x4 acc[8][4];
  #pragma unroll
  for (int i = 0; i < 8; ++i)
    #pragma unroll
    for (int j = 0; j < 4; ++j)
      acc[i][j] = f32x4{0.f, 0.f, 0.f, 0.f};

  auto STAGE = [&](int slot, int kt) {
    #pragma unroll
    for (int j = 0; j < 2; ++j) {
      const int rb = j * 128 + wv * 16;          // wave-uniform row base
      const int arow = rb + srow;
      {
        const int gch = sch ^ ((arow >> 1) & 3);
        const u16* ga = Ab + (size_t)(m0 + arow) * lda + kt * 32 + gch * 8;
        __builtin_amdgcn_global_load_lds((gu32*)ga, (su32*)(As + (slot * 256 + rb) * 32), 16, 0, 0);
      }
      {
        const int gch = sch ^ ((arow >> 1) & 3);
        const u16* gb = Bb + (size_t)(n0 + arow) * ldb + kt * 32 + gch * 8;
        __builtin_amdgcn_global_load_lds((gu32*)gb, (su32*)(Bs + (slot * 256 + rb) * 32), 16, 0, 0);
      }
    }
  };

  STAGE(0, 0); STAGE(1, 1); STAGE(2, 2);   // depth-3 prologue

  for (int kt = 0; kt < nk; ++kt) {
    const int slot = kt & 3;
    if (kt < nk - 2)        asm volatile("s_waitcnt vmcnt(8)" ::: "memory");
    else if (kt == nk - 2)  asm volatile("s_waitcnt vmcnt(4)" ::: "memory");
    else                    asm volatile("s_waitcnt vmcnt(0)" ::: "memory");
    __builtin_amdgcn_s_barrier();

    const u16* Asl = As + slot * (256 * 32);
    const u16* Bsl = Bs + slot * (256 * 32);
    bf16x8 af[8], bf[4];
    #pragma unroll
    for (int mf = 0; mf < 8; ++mf)
      af[mf] = *(const bf16x8*)(Asl + (wm + mf * 16 + lr) * 32 + cA);
    #pragma unroll
    for (int nf = 0; nf < 4; ++nf)
      bf[nf] = *(const bf16x8*)(Bsl + (wn + nf * 16 + lr) * 32 + cB);

    if (kt + 3 < nk) STAGE((kt + 3) & 3, kt + 3);

    __builtin_amdgcn_s_setprio(1);
    #pragma unroll
    for (int mf = 0; mf < 8; ++mf)
      #pragma unroll
      for (int nf = 0; nf < 4; ++nf)
        acc[mf][nf] = __builtin_amdgcn_mfma_f32_16x16x32_bf16(af[mf], bf[nf], acc[mf][nf], 0, 0, 0);
    __builtin_amdgcn_s_setprio(0);
    asm volatile("s_waitcnt lgkmcnt(0)" ::: "memory");
  }

  u16*   C16 = (u16*)Cg + (size_t)b * sC;
  float* C32 = (float*)Cg + (size_t)b * sC;
  const float* xb = (EPI == EP_FINAL) ? (ep_x + (size_t)b * sX) : nullptr;
  #pragma unroll
  for (int mf = 0; mf < 8; ++mf) {
    #pragma unroll
    for (int nf = 0; nf < 4; ++nf) {
      #pragma unroll
      for (int r = 0; r < 4; ++r) {
        int row = m0 + wm + mf * 16 + lg * 4 + r;
        int col = n0 + wn + nf * 16 + lr;
        float v = acc[mf][nf][r];
        if constexpr (EPI == EP_FG) {
          v = v * ep_scale[col] + ep_bias[col];
          if (col < 1024) v = fmaxf(v, 0.f);
          C16[(size_t)row * ldc + col] = f2bf(v);
        } else if constexpr (EPI == EP_SCORE) {
          C32[(size_t)row * ldc + col] = v * fscale;
        } else if constexpr (EPI == EP_BF16) {
          C16[(size_t)row * ldc + col] = f2bf(v);
        } else {
          v += ep_bias[row] + xb[(size_t)row * ldc + col];
          C32[(size_t)row * ldc + col] = v;
        }
      }
    }
  }
}

// ---------------- softmax (rows of 2304, fp32 in place + bf16 copy, vectorized) ----------------
__global__ __launch_bounds__(256) void softmax_k(float* __restrict__ attn, u16* __restrict__ P) {
  float* r = attn + (size_t)blockIdx.x * N_;
  u16* pr = P + (size_t)blockIdx.x * N_;
  const int tid = threadIdx.x;
  float4 v0 = *(const float4*)&r[tid * 4];
  float4 v1 = *(const float4*)&r[1024 + tid * 4];
  float  v2 = r[2048 + tid];
  float mx = fmaxf(fmaxf(fmaxf(v0.x, v0.y), fmaxf(v0.z, v0.w)),
                   fmaxf(fmaxf(fmaxf(v1.x, v1.y), fmaxf(v1.z, v1.w)), v2));
  #pragma unroll
  for (int o = 32; o; o >>= 1) mx = fmaxf(mx, __shfl_xor(mx, o));
  __shared__ float red[4], red2[4];
  if ((tid & 63) == 0) red[tid >> 6] = mx;
  __syncthreads();
  mx = fmaxf(fmaxf(red[0], red[1]), fmaxf(red[2], red[3]));
  v0.x = __expf(v0.x - mx); v0.y = __expf(v0.y - mx);
  v0.z = __expf(v0.z - mx); v0.w = __expf(v0.w - mx);
  v1.x = __expf(v1.x - mx); v1.y = __expf(v1.y - mx);
  v1.z = __expf(v1.z - mx); v1.w = __expf(v1.w - mx);
  v2 = __expf(v2 - mx);
  float s = v0.x + v0.y + v0.z + v0.w + v1.x + v1.y + v1.z + v1.w + v2;
  #pragma unroll
  for (int o = 32; o; o >>= 1) s += __shfl_xor(s, o);
  if ((tid & 63) == 0) red2[tid >> 6] = s;
  __syncthreads();
  s = red2[0] + red2[1] + red2[2] + red2[3];
  float inv = 1.0f / s;
  v0.x *= inv; v0.y *= inv; v0.z *= inv; v0.w *= inv;
  v1.x *= inv; v1.y *= inv; v1.z *= inv; v1.w *= inv;
  v2 *= inv;
  *(float4*)&r[tid * 4] = v0;
  *(float4*)&r[1024 + tid * 4] = v1;
  r[2048 + tid] = v2;
  u16x4 p0; p0[0] = f2bf(v0.x); p0[1] = f2bf(v0.y); p0[2] = f2bf(v0.z); p0[3] = f2bf(v0.w);
  u16x4 p1; p1[0] = f2bf(v1.x); p1[1] = f2bf(v1.y); p1[2] = f2bf(v1.z); p1[3] = f2bf(v1.w);
  *(u16x4*)&pr[tid * 4] = p0;
  *(u16x4*)&pr[1024 + tid * 4] = p1;
  pr[2048 + tid] = f2bf(v2);
}

// ---------------- launch ----------------
extern "C" void kernel_launch(void* const* d_in, const int* in_sizes, int n_in,
                              void* d_out, int out_size, void* d_ws, size_t ws_size,
                              hipStream_t stream) {
  const float* x    = (const float*)d_in[0];
  const float* f_w  = (const float*)d_in[1];
  const float* f_b  = (const float*)d_in[2];
  const float* f_ga = (const float*)d_in[3];
  const float* f_be = (const float*)d_in[4];
  const float* f_me = (const float*)d_in[5];
  const float* f_va = (const float*)d_in[6];
  const float* g_w  = (const float*)d_in[7];
  const float* g_b  = (const float*)d_in[8];
  const float* g_ga = (const float*)d_in[9];
  const float* g_be = (const float*)d_in[10];
  const float* g_me = (const float*)d_in[11];
  const float* g_va = (const float*)d_in[12];
  const float* h_w  = (const float*)d_in[13];
  const float* h_b  = (const float*)d_in[14];
  const float* v_w  = (const float*)d_in[15];
  const float* v_b  = (const float*)d_in[16];

  float* out0 = (float*)d_out;
  float* attn = out0 + (size_t)B_ * C_ * N_;   // second output region

  // workspace carve (~180 MB; P reuses dead xT+fghT regions after G2)
  char* p = (char*)d_ws;
  u16* xT   = (u16*)p; p += (size_t)B_ * N_ * C_ * 2;       // 75.5 MB (dead after G1)
  u16* fghT = (u16*)p; p += (size_t)B_ * N_ * 1536 * 2;     // 56.6 MB (dead after G2 & h-copy)
  u16* hx   = (u16*)p; p += (size_t)B_ * MID_ * N_ * 2;     // 18.9 MB
  u16* ZT   = (u16*)p; p += (size_t)B_ * N_ * MID_ * 2;     // 18.9 MB
  u16* Wall = (u16*)p; p += (size_t)1536 * C_ * 2;          // 6.3 MB
  u16* vwb  = (u16*)p; p += (size_t)C_ * MID_ * 2;          // 2.1 MB
  float* sc = (float*)p; p += 1536 * 4;
  float* bi = (float*)p; p += 1536 * 4;
  u16* P = xT;                                              // 85 MB, overlaps xT+fghT head

  hipFuncSetAttribute((const void*)gemm3_kernel<EP_FG>,    hipFuncAttributeMaxDynamicSharedMemorySize, 131072);
  hipFuncSetAttribute((const void*)gemm3_kernel<EP_SCORE>, hipFuncAttributeMaxDynamicSharedMemorySize, 131072);
  hipFuncSetAttribute((const void*)gemm3_kernel<EP_BF16>,  hipFuncAttributeMaxDynamicSharedMemorySize, 131072);
  hipFuncSetAttribute((const void*)gemm3_kernel<EP_FINAL>, hipFuncAttributeMaxDynamicSharedMemorySize, 131072);

  prep_wall_k<<<(1536 * 2048 + 255) / 256, 256, 0, stream>>>(f_w, g_w, h_w, Wall);
  prep_vw_k<<<(2048 * 512 + 255) / 256, 256, 0, stream>>>(v_w, vwb);
  prep_sb_k<<<6, 256, 0, stream>>>(f_b, f_ga, f_be, f_me, f_va,
                                   g_b, g_ga, g_be, g_me, g_va, h_b, sc, bi);
  transpose_x_k<<<dim3(N_ / 64, C_ / 64, B_), 256, 0, stream>>>(x, xT);

  // G1: fghT[n][c'] = xT[n][:] . Wall[c'][:]  (M=2304,N=1536,K=2048) + BN/ReLU/h_b -> bf16
  gemm3_kernel<EP_FG><<<dim3(1536 / 256, N_ / 256, B_), 512, 131072, stream>>>(
      xT, C_, (long long)N_ * C_, Wall, C_, 0,
      fghT, 1536, (long long)N_ * 1536, C_, sc, bi, nullptr, 0, 0.f);

  // hx[c][n] = fghT[n][1024+c]  (bf16 transpose, 38 MB)
  transpose_h_k<<<dim3(N_ / 32, MID_ / 32, B_), 256, 0, stream>>>(fghT, hx);

  // G2: scores[n][m] = fT[n][:] . gT[m][:] * mid^-0.5  (M=N=2304,K=512) -> f32 attn
  const float fscale = 0.044194173824159216f;  // 512^-0.5
  gemm3_kernel<EP_SCORE><<<dim3(N_ / 256, N_ / 256, B_), 512, 131072, stream>>>(
      fghT, 1536, (long long)N_ * 1536, fghT + 512, 1536, (long long)N_ * 1536,
      attn, N_, (long long)N_ * N_, MID_, nullptr, nullptr, nullptr, 0, fscale);

  softmax_k<<<B_ * N_, 256, 0, stream>>>(attn, P);

  // G3: ZT[n][c] = P[n][:] . hx[c][:]  (M=2304,N=512,K=2304) -> bf16
  gemm3_kernel<EP_BF16><<<dim3(MID_ / 256, N_ / 256, B_), 512, 131072, stream>>>(
      P, N_, (long long)N_ * N_, hx, N_, (long long)MID_ * N_,
      ZT, MID_, (long long)N_ * MID_, N_, nullptr, nullptr, nullptr, 0, 0.f);

  // G5: out[o][n] = vwb[o][:] . ZT[n][:] + v_b[o] + x[o][n]  (M=2048,N=2304,K=512) -> f32
  gemm3_kernel<EP_FINAL><<<dim3(N_ / 256, C_ / 256, B_), 512, 131072, stream>>>(
      vwb, MID_, 0, ZT, MID_, (long long)N_ * MID_,
      out0, N_, (long long)C_ * N_, MID_, nullptr, v_b, x, (long long)C_ * N_, 0.f);
}

// Round 5
// 514.040 us; speedup vs baseline: 1.1976x; 1.0093x over previous
//
#include <hip/hip_runtime.h>
#include <math.h>

typedef unsigned short u16;
typedef unsigned short u16x8 __attribute__((ext_vector_type(8)));
typedef __bf16 bf16x8 __attribute__((ext_vector_type(8)));
typedef float f32x4 __attribute__((ext_vector_type(4)));

typedef __attribute__((address_space(1))) const unsigned int gu32;
typedef __attribute__((address_space(3))) unsigned int su32;

#define B_ 8
#define C_ 2048
#define MID_ 512
#define N_ 2304

// compiler-fence on both sides of a raw barrier (keeps C++ LDS ops ordered vs it)
#define BAR() do { asm volatile("" ::: "memory"); __builtin_amdgcn_s_barrier(); asm volatile("" ::: "memory"); } while (0)

#define QMFMA(AV, BV, MO, NO)                                                             \
  { _Pragma("unroll") for (int mfi = 0; mfi < 4; ++mfi) {                                 \
      _Pragma("unroll") for (int nfi = 0; nfi < 2; ++nfi) {                               \
        acc[MO + mfi][NO + nfi] = __builtin_amdgcn_mfma_f32_16x16x32_bf16(                \
            AV[0][mfi], BV[0][nfi], acc[MO + mfi][NO + nfi], 0, 0, 0);                    \
        acc[MO + mfi][NO + nfi] = __builtin_amdgcn_mfma_f32_16x16x32_bf16(                \
            AV[1][mfi], BV[1][nfi], acc[MO + mfi][NO + nfi], 0, 0, 0); } } }

static __device__ __forceinline__ u16 f2bf(float f) {
  union { float f; unsigned u; } c; c.f = f;
  unsigned u = c.u;
  u += 0x7fffu + ((u >> 16) & 1u);   // round to nearest even
  return (u16)(u >> 16);
}
static __device__ __forceinline__ float bf2f(u16 x) {
  union { unsigned u; float f; } c; c.u = ((unsigned)x) << 16; return c.f;
}

// ---------------- prep kernels ----------------
__global__ __launch_bounds__(256) void prep_wall_k(
    const float* __restrict__ fw, const float* __restrict__ gw,
    const float* __restrict__ hw, u16* __restrict__ wall) {
  int idx = blockIdx.x * 256 + threadIdx.x;
  if (idx >= 1536 * 2048) return;
  int r = idx >> 11;
  float v = (r < 512) ? fw[idx] : (r < 1024) ? gw[idx - (512 << 11)] : hw[idx - (1024 << 11)];
  wall[idx] = f2bf(v);
}

__global__ __launch_bounds__(256) void prep_vw_k(const float* __restrict__ vw, u16* __restrict__ o) {
  int idx = blockIdx.x * 256 + threadIdx.x;
  if (idx < 2048 * 512) o[idx] = f2bf(vw[idx]);
}

__global__ __launch_bounds__(256) void prep_sb_k(
    const float* fb, const float* fg, const float* fbe, const float* fm, const float* fv,
    const float* gb, const float* gg, const float* gbe, const float* gm, const float* gv,
    const float* hb, float* __restrict__ scale, float* __restrict__ bias) {
  int i = blockIdx.x * 256 + threadIdx.x;
  if (i >= 1536) return;
  if (i < 512) {
    float inv = fg[i] / sqrtf(fv[i] + 1e-5f);
    scale[i] = inv; bias[i] = fb[i] * inv + fbe[i] - fm[i] * inv;
  } else if (i < 1024) {
    int j = i - 512;
    float inv = gg[j] / sqrtf(gv[j] + 1e-5f);
    scale[i] = inv; bias[i] = gb[j] * inv + gbe[j] - gm[j] * inv;
  } else {
    scale[i] = 1.0f; bias[i] = hb[i - 1024];
  }
}

// x [B][C][N] f32 -> xT [B][N][C] bf16   (64x64 tile, float4 loads, 16B stores)
__global__ __launch_bounds__(256) void transpose_x_k(const float* __restrict__ x, u16* __restrict__ xT) {
  __shared__ float tile[64][68];
  const int b = blockIdx.z;
  const int n0 = blockIdx.x * 64, c0 = blockIdx.y * 64;
  const float* xb = x + (size_t)b * C_ * N_;
  u16* xTb = xT + (size_t)b * N_ * C_;
  const int r = threadIdx.x >> 2, q = threadIdx.x & 3;
  #pragma unroll
  for (int j = 0; j < 4; ++j) {
    float4 v = *(const float4*)&xb[(size_t)(c0 + r) * N_ + n0 + (q + 4 * j) * 4];
    *(float4*)&tile[r][(q + 4 * j) * 4] = v;
  }
  __syncthreads();
  #pragma unroll
  for (int g = 0; g < 2; ++g) {
    const int cl = (q * 2 + g) * 8;
    u16x8 w;
    #pragma unroll
    for (int e = 0; e < 8; ++e) w[e] = f2bf(tile[cl + e][r]);
    *(u16x8*)&xTb[(size_t)(n0 + r) * C_ + c0 + cl] = w;
  }
}

// fghT h-columns [B][N][1024+c] -> hx [B][512][N]  (bf16 32x32 tile transpose)
__global__ __launch_bounds__(256) void transpose_h_k(const u16* __restrict__ fghT, u16* __restrict__ hx) {
  __shared__ u16 tile[32][33];
  const int b = blockIdx.z;
  const int n0 = blockIdx.x * 32, c0 = blockIdx.y * 32;
  const u16* src = fghT + (size_t)b * N_ * 1536;
  u16* dst = hx + (size_t)b * MID_ * N_;
  const int tx = threadIdx.x & 31, ty = threadIdx.x >> 5;
  #pragma unroll
  for (int i = 0; i < 4; ++i)
    tile[ty + i * 8][tx] = src[(size_t)(n0 + ty + i * 8) * 1536 + 1024 + c0 + tx];
  __syncthreads();
  #pragma unroll
  for (int i = 0; i < 4; ++i)
    dst[(size_t)(c0 + ty + i * 8) * N_ + n0 + tx] = tile[tx][ty + i * 8];
}

// ---------------- GEMM: 256x256, BK=64, 2-buf LDS, 4-phase interleave, counted vmcnt ----
// OUT[M,N] = A[M,K] * B^T[N,K]; bf16 row-major contiguous-K operands.
// 512 thr = 8 waves (2M x 4N); per-wave 128x64 = 8x4 frags. LDS 2 x (32KB A + 32KB B).
// Per K-tile kt (buf p = kt&1), phases (quadrant = (mh,nh)):
//  ph0: ds_read a(mh0) 8x b128 + b(nh0) 4x        | BAR | MFMA q(0,0) | BAR
//  ph1: ds_read b(nh1) 4x                          | BAR | MFMA q(0,1) | BAR
//  ph2: ds_read a(mh1) 8x ; STAGE B(kt+2) 4 loads  | BAR | MFMA q(1,0) | BAR
//  ph3:                    STAGE A(kt+2) 4 loads   | BAR | MFMA q(1,1) | BAR
// Ledger: B reads of kt all done at ph1-close -> stage B at ph2 safe; A reads done at
// ph2-close -> stage A at ph3 safe. Loop-top vmcnt(8) leaves kt+1's 8 loads in flight,
// drains kt's (issued during kt-2). Last tile waits vmcnt(0). Never drains mid-stream.
// Swizzle (both-sides): LDS (row, chunk16B) holds global chunk (chunk ^ (row&7));
// pre-swizzled global source at stage, XOR'd ds_read address -> uniform 8 dwords/bank.
#define EP_FG 0       // v*scale[col]+bias[col], relu if col<1024, store bf16
#define EP_SCALE16 1  // f2bf(v*fscale)
#define EP_FINAL 2    // v+bias[row]+x[row][col], store f32

template<int EPI>
__global__ __launch_bounds__(512, 2) void gemm4_kernel(
    const u16* __restrict__ Ag, int lda, long long sA,
    const u16* __restrict__ Bg, int ldb, long long sB,
    void* __restrict__ Cg, int ldc, long long sC, int K,
    const float* __restrict__ ep_scale, const float* __restrict__ ep_bias,
    const float* __restrict__ ep_x, long long sX, float fscale)
{
  extern __shared__ __align__(16) u16 smem[];
  u16* As = smem;                    // [2][256*64]
  u16* Bs = smem + 2 * 256 * 64;     // [2][256*64]

  const int tid = threadIdx.x;
  const int lane = tid & 63;
  const int wv = tid >> 6;           // 0..7
  const int b = blockIdx.z;
  const int m0 = blockIdx.y * 256;
  const int n0 = blockIdx.x * 256;
  const int wm = (wv >> 2) * 128;    // 0 / 128
  const int wn = (wv & 3) * 64;      // 0,64,128,192
  const int lr = lane & 15, lg = lane >> 4;

  const u16* Ab = Ag + (size_t)b * sA;
  const u16* Bb = Bg + (size_t)b * sB;
  const int nk = K >> 6;             // K-tiles of 64

  // staging: wave instr j covers rows j*64 + wv*8 + (lane>>3), chunk lane&7 (linear LDS)
  const int srow = lane >> 3;                    // 0..7 == row&7 for our row bases
  const int sksw = ((lane & 7) ^ srow) * 8;      // pre-swizzled global k-offset (elems)

  // ds_read swizzled chunk offsets (elems) for k-step 0 / 1
  const int rdsw0 = ((0 + lg) ^ (lr & 7)) * 8;
  const int rdsw1 = ((4 + lg) ^ (lr & 7)) * 8;

  f32x4 acc[8][4];
  #pragma unroll
  for (int i = 0; i < 8; ++i)
    #pragma unroll
    for (int j = 0; j < 4; ++j)
      acc[i][j] = f32x4{0.f, 0.f, 0.f, 0.f};

  auto STAGE_A = [&](int p2, int t) {
    #pragma unroll
    for (int j = 0; j < 4; ++j) {
      const int rb = j * 64 + wv * 8;
      const u16* g = Ab + (size_t)(m0 + rb + srow) * lda + t * 64 + sksw;
      __builtin_amdgcn_global_load_lds((gu32*)g, (su32*)(As + p2 * 16384 + rb * 64), 16, 0, 0);
    }
  };
  auto STAGE_B = [&](int p2, int t) {
    #pragma unroll
    for (int j = 0; j < 4; ++j) {
      const int rb = j * 64 + wv * 8;
      const u16* g = Bb + (size_t)(n0 + rb + srow) * ldb + t * 64 + sksw;
      __builtin_amdgcn_global_load_lds((gu32*)g, (su32*)(Bs + p2 * 16384 + rb * 64), 16, 0, 0);
    }
  };

  STAGE_A(0, 0); STAGE_B(0, 0);
  if (nk > 1) { STAGE_A(1, 1); STAGE_B(1, 1); }

  for (int kt = 0; kt < nk; ++kt) {
    const int p = kt & 1;
    if (kt + 1 < nk) asm volatile("s_waitcnt vmcnt(8)" ::: "memory");
    else             asm volatile("s_waitcnt vmcnt(0)" ::: "memory");
    BAR();

    const u16* Asl = As + p * 16384;
    const u16* Bsl = Bs + p * 16384;
    const bool st = (kt + 2) < nk;
    const int ps = (kt + 2) & 1;

    bf16x8 aV[2][4], bLo[2][2], bHi[2][2];

    // ---- ph0: a(mh0), b(nh0) ----
    #pragma unroll
    for (int ks = 0; ks < 2; ++ks) {
      const int ro = ks ? rdsw1 : rdsw0;
      #pragma unroll
      for (int i = 0; i < 4; ++i)
        aV[ks][i] = *(const bf16x8*)(Asl + (wm + i * 16 + lr) * 64 + ro);
      #pragma unroll
      for (int i = 0; i < 2; ++i)
        bLo[ks][i] = *(const bf16x8*)(Bsl + (wn + i * 16 + lr) * 64 + ro);
    }
    BAR();
    __builtin_amdgcn_s_setprio(1);
    QMFMA(aV, bLo, 0, 0);
    __builtin_amdgcn_s_setprio(0);
    BAR();

    // ---- ph1: b(nh1) ----
    #pragma unroll
    for (int ks = 0; ks < 2; ++ks) {
      const int ro = ks ? rdsw1 : rdsw0;
      #pragma unroll
      for (int i = 0; i < 2; ++i)
        bHi[ks][i] = *(const bf16x8*)(Bsl + (wn + 32 + i * 16 + lr) * 64 + ro);
    }
    BAR();
    __builtin_amdgcn_s_setprio(1);
    QMFMA(aV, bHi, 0, 2);
    __builtin_amdgcn_s_setprio(0);
    BAR();

    // ---- ph2: a(mh1); stage B(kt+2) ----
    #pragma unroll
    for (int ks = 0; ks < 2; ++ks) {
      const int ro = ks ? rdsw1 : rdsw0;
      #pragma unroll
      for (int i = 0; i < 4; ++i)
        aV[ks][i] = *(const bf16x8*)(Asl + (wm + 64 + i * 16 + lr) * 64 + ro);
    }
    if (st) STAGE_B(ps, kt + 2);
    BAR();
    __builtin_amdgcn_s_setprio(1);
    QMFMA(aV, bLo, 4, 0);
    __builtin_amdgcn_s_setprio(0);
    BAR();

    // ---- ph3: stage A(kt+2) ----
    if (st) STAGE_A(ps, kt + 2);
    BAR();
    __builtin_amdgcn_s_setprio(1);
    QMFMA(aV, bHi, 4, 2);
    __builtin_amdgcn_s_setprio(0);
    BAR();
  }

  // epilogue: D row = 4*lg + r, col = lr within each 16x16 fragment
  u16*   C16 = (u16*)Cg + (size_t)b * sC;
  float* C32 = (float*)Cg + (size_t)b * sC;
  const float* xb = (EPI == EP_FINAL) ? (ep_x + (size_t)b * sX) : nullptr;
  #pragma unroll
  for (int mf = 0; mf < 8; ++mf) {
    #pragma unroll
    for (int nf = 0; nf < 4; ++nf) {
      #pragma unroll
      for (int r = 0; r < 4; ++r) {
        int row = m0 + wm + mf * 16 + lg * 4 + r;
        int col = n0 + wn + nf * 16 + lr;
        float v = acc[mf][nf][r];
        if constexpr (EPI == EP_FG) {
          v = v * ep_scale[col] + ep_bias[col];
          if (col < 1024) v = fmaxf(v, 0.f);
          C16[(size_t)row * ldc + col] = f2bf(v);
        } else if constexpr (EPI == EP_SCALE16) {
          C16[(size_t)row * ldc + col] = f2bf(v * fscale);
        } else {
          v += ep_bias[row] + xb[(size_t)row * ldc + col];
          C32[(size_t)row * ldc + col] = v;
        }
      }
    }
  }
}

// -------- softmax: read bf16 scores, write f32 attn + bf16 P in place over scores -----
__global__ __launch_bounds__(256) void softmax_k(u16* __restrict__ SP, float* __restrict__ attn) {
  u16* sp = SP + (size_t)blockIdx.x * N_;
  float* ar = attn + (size_t)blockIdx.x * N_;
  const int tid = threadIdx.x;
  u16x8 s8 = *(const u16x8*)&sp[tid * 8];
  u16 st = sp[2048 + tid];
  float w[8], wt = bf2f(st);
  #pragma unroll
  for (int j = 0; j < 8; ++j) w[j] = bf2f(s8[j]);
  float mx = wt;
  #pragma unroll
  for (int j = 0; j < 8; ++j) mx = fmaxf(mx, w[j]);
  #pragma unroll
  for (int o = 32; o; o >>= 1) mx = fmaxf(mx, __shfl_xor(mx, o));
  __shared__ float red[4], red2[4];
  if ((tid & 63) == 0) red[tid >> 6] = mx;
  __syncthreads();
  mx = fmaxf(fmaxf(red[0], red[1]), fmaxf(red[2], red[3]));
  float s = 0.f;
  #pragma unroll
  for (int j = 0; j < 8; ++j) { w[j] = __expf(w[j] - mx); s += w[j]; }
  wt = __expf(wt - mx); s += wt;
  #pragma unroll
  for (int o = 32; o; o >>= 1) s += __shfl_xor(s, o);
  if ((tid & 63) == 0) red2[tid >> 6] = s;
  __syncthreads();
  s = red2[0] + red2[1] + red2[2] + red2[3];
  float inv = 1.0f / s;
  #pragma unroll
  for (int j = 0; j < 8; ++j) w[j] *= inv;
  wt *= inv;
  float4 o0 = {w[0], w[1], w[2], w[3]}, o1 = {w[4], w[5], w[6], w[7]};
  *(float4*)&ar[tid * 8] = o0;
  *(float4*)&ar[tid * 8 + 4] = o1;
  ar[2048 + tid] = wt;
  u16x8 p8;
  #pragma unroll
  for (int j = 0; j < 8; ++j) p8[j] = f2bf(w[j]);
  *(u16x8*)&sp[tid * 8] = p8;
  sp[2048 + tid] = f2bf(wt);
}

// ---------------- launch ----------------
extern "C" void kernel_launch(void* const* d_in, const int* in_sizes, int n_in,
                              void* d_out, int out_size, void* d_ws, size_t ws_size,
                              hipStream_t stream) {
  const float* x    = (const float*)d_in[0];
  const float* f_w  = (const float*)d_in[1];
  const float* f_b  = (const float*)d_in[2];
  const float* f_ga = (const float*)d_in[3];
  const float* f_be = (const float*)d_in[4];
  const float* f_me = (const float*)d_in[5];
  const float* f_va = (const float*)d_in[6];
  const float* g_w  = (const float*)d_in[7];
  const float* g_b  = (const float*)d_in[8];
  const float* g_ga = (const float*)d_in[9];
  const float* g_be = (const float*)d_in[10];
  const float* g_me = (const float*)d_in[11];
  const float* g_va = (const float*)d_in[12];
  const float* h_w  = (const float*)d_in[13];
  const float* h_b  = (const float*)d_in[14];
  const float* v_w  = (const float*)d_in[15];
  const float* v_b  = (const float*)d_in[16];

  float* out0 = (float*)d_out;
  float* attn = out0 + (size_t)B_ * C_ * N_;   // second output region

  // workspace carve (~263 MB)
  char* p = (char*)d_ws;
  u16* xT   = (u16*)p; p += (size_t)B_ * N_ * C_ * 2;       // 75.5 MB
  u16* fghT = (u16*)p; p += (size_t)B_ * N_ * 1536 * 2;     // 56.6 MB
  u16* hx   = (u16*)p; p += (size_t)B_ * MID_ * N_ * 2;     // 18.9 MB
  u16* ZT   = (u16*)p; p += (size_t)B_ * N_ * MID_ * 2;     // 18.9 MB
  u16* Wall = (u16*)p; p += (size_t)1536 * C_ * 2;          // 6.3 MB
  u16* vwb  = (u16*)p; p += (size_t)C_ * MID_ * 2;          // 2.1 MB
  float* sc = (float*)p; p += 1536 * 4;
  float* bi = (float*)p; p += 1536 * 4;
  u16* SP   = (u16*)p; p += (size_t)B_ * N_ * N_ * 2;       // 85 MB (scores bf16 -> P bf16)

  hipFuncSetAttribute((const void*)gemm4_kernel<EP_FG>,      hipFuncAttributeMaxDynamicSharedMemorySize, 131072);
  hipFuncSetAttribute((const void*)gemm4_kernel<EP_SCALE16>, hipFuncAttributeMaxDynamicSharedMemorySize, 131072);
  hipFuncSetAttribute((const void*)gemm4_kernel<EP_FINAL>,   hipFuncAttributeMaxDynamicSharedMemorySize, 131072);

  prep_wall_k<<<(1536 * 2048 + 255) / 256, 256, 0, stream>>>(f_w, g_w, h_w, Wall);
  prep_vw_k<<<(2048 * 512 + 255) / 256, 256, 0, stream>>>(v_w, vwb);
  prep_sb_k<<<6, 256, 0, stream>>>(f_b, f_ga, f_be, f_me, f_va,
                                   g_b, g_ga, g_be, g_me, g_va, h_b, sc, bi);
  transpose_x_k<<<dim3(N_ / 64, C_ / 64, B_), 256, 0, stream>>>(x, xT);

  // G1: fghT[n][c'] = xT[n][:] . Wall[c'][:]  (M=2304,N=1536,K=2048) + BN/ReLU/h_b -> bf16
  gemm4_kernel<EP_FG><<<dim3(1536 / 256, N_ / 256, B_), 512, 131072, stream>>>(
      xT, C_, (long long)N_ * C_, Wall, C_, 0,
      fghT, 1536, (long long)N_ * 1536, C_, sc, bi, nullptr, 0, 0.f);

  // hx[c][n] = fghT[n][1024+c]  (bf16 transpose)
  transpose_h_k<<<dim3(N_ / 32, MID_ / 32, B_), 256, 0, stream>>>(fghT, hx);

  // G2: scores bf16 = fT . gT^T * mid^-0.5  (M=N=2304,K=512)
  const float fscale = 0.044194173824159216f;  // 512^-0.5
  gemm4_kernel<EP_SCALE16><<<dim3(N_ / 256, N_ / 256, B_), 512, 131072, stream>>>(
      fghT, 1536, (long long)N_ * 1536, fghT + 512, 1536, (long long)N_ * 1536,
      SP, N_, (long long)N_ * N_, MID_, nullptr, nullptr, nullptr, 0, fscale);

  softmax_k<<<B_ * N_, 256, 0, stream>>>(SP, attn);

  // G3: ZT[n][c] = P[n][:] . hx[c][:]  (M=2304,N=512,K=2304) -> bf16
  gemm4_kernel<EP_SCALE16><<<dim3(MID_ / 256, N_ / 256, B_), 512, 131072, stream>>>(
      SP, N_, (long long)N_ * N_, hx, N_, (long long)MID_ * N_,
      ZT, MID_, (long long)N_ * MID_, N_, nullptr, nullptr, nullptr, 0, 1.0f);

  // G5: out[o][n] = vwb[o][:] . ZT[n][:] + v_b[o] + x[o][n]  (M=2048,N=2304,K=512) -> f32
  gemm4_kernel<EP_FINAL><<<dim3(N_ / 256, C_ / 256, B_), 512, 131072, stream>>>(
      vwb, MID_, 0, ZT, MID_, (long long)N_ * MID_,
      out0, N_, (long long)C_ * N_, MID_, nullptr, v_b, x, (long long)C_ * N_, 0.f);
}

// Round 6
// 505.214 us; speedup vs baseline: 1.2185x; 1.0175x over previous
//
#include <hip/hip_runtime.h>
#include <math.h>

typedef unsigned short u16;
typedef unsigned short u16x8 __attribute__((ext_vector_type(8)));
typedef __bf16 bf16x8 __attribute__((ext_vector_type(8)));
typedef float f32x4 __attribute__((ext_vector_type(4)));

typedef __attribute__((address_space(1))) const unsigned int gu32;
typedef __attribute__((address_space(3))) unsigned int su32;

#define B_ 8
#define C_ 2048
#define MID_ 512
#define N_ 2304

#define BAR() do { asm volatile("" ::: "memory"); __builtin_amdgcn_s_barrier(); asm volatile("" ::: "memory"); } while (0)

#define QMFMA(AV, BV, MO, NO)                                                             \
  { _Pragma("unroll") for (int mfi = 0; mfi < 4; ++mfi) {                                 \
      _Pragma("unroll") for (int nfi = 0; nfi < 2; ++nfi) {                               \
        acc[MO + mfi][NO + nfi] = __builtin_amdgcn_mfma_f32_16x16x32_bf16(                \
            AV[0][mfi], BV[0][nfi], acc[MO + mfi][NO + nfi], 0, 0, 0);                    \
        acc[MO + mfi][NO + nfi] = __builtin_amdgcn_mfma_f32_16x16x32_bf16(                \
            AV[1][mfi], BV[1][nfi], acc[MO + mfi][NO + nfi], 0, 0, 0); } } }

static __device__ __forceinline__ u16 f2bf(float f) {
  union { float f; unsigned u; } c; c.f = f;
  unsigned u = c.u;
  u += 0x7fffu + ((u >> 16) & 1u);   // round to nearest even
  return (u16)(u >> 16);
}
static __device__ __forceinline__ float bf2f(u16 x) {
  union { unsigned u; float f; } c; c.u = ((unsigned)x) << 16; return c.f;
}

// ---------------- prep kernels ----------------
__global__ __launch_bounds__(256) void prep_wall_k(
    const float* __restrict__ fw, const float* __restrict__ gw,
    const float* __restrict__ hw, u16* __restrict__ wall) {
  int idx = blockIdx.x * 256 + threadIdx.x;
  if (idx >= 1536 * 2048) return;
  int r = idx >> 11;
  float v = (r < 512) ? fw[idx] : (r < 1024) ? gw[idx - (512 << 11)] : hw[idx - (1024 << 11)];
  wall[idx] = f2bf(v);
}

__global__ __launch_bounds__(256) void prep_vw_k(const float* __restrict__ vw, u16* __restrict__ o) {
  int idx = blockIdx.x * 256 + threadIdx.x;
  if (idx < 2048 * 512) o[idx] = f2bf(vw[idx]);
}

// BN fold; f-columns additionally pre-scaled by 512^-0.5 (folds the score scale into f)
__global__ __launch_bounds__(256) void prep_sb_k(
    const float* fb, const float* fg, const float* fbe, const float* fm, const float* fv,
    const float* gb, const float* gg, const float* gbe, const float* gm, const float* gv,
    const float* hb, float* __restrict__ scale, float* __restrict__ bias) {
  int i = blockIdx.x * 256 + threadIdx.x;
  if (i >= 1536) return;
  const float FS = 0.044194173824159216f;  // 512^-0.5
  if (i < 512) {
    float inv = fg[i] / sqrtf(fv[i] + 1e-5f);
    scale[i] = inv * FS; bias[i] = (fb[i] * inv + fbe[i] - fm[i] * inv) * FS;
  } else if (i < 1024) {
    int j = i - 512;
    float inv = gg[j] / sqrtf(gv[j] + 1e-5f);
    scale[i] = inv; bias[i] = gb[j] * inv + gbe[j] - gm[j] * inv;
  } else {
    scale[i] = 1.0f; bias[i] = hb[i - 1024];
  }
}

// x [B][C][N] f32 -> xT [B][N][C] bf16   (64x64 tile, float4 loads, 16B stores)
__global__ __launch_bounds__(256) void transpose_x_k(const float* __restrict__ x, u16* __restrict__ xT) {
  __shared__ float tile[64][68];
  const int b = blockIdx.z;
  const int n0 = blockIdx.x * 64, c0 = blockIdx.y * 64;
  const float* xb = x + (size_t)b * C_ * N_;
  u16* xTb = xT + (size_t)b * N_ * C_;
  const int r = threadIdx.x >> 2, q = threadIdx.x & 3;
  #pragma unroll
  for (int j = 0; j < 4; ++j) {
    float4 v = *(const float4*)&xb[(size_t)(c0 + r) * N_ + n0 + (q + 4 * j) * 4];
    *(float4*)&tile[r][(q + 4 * j) * 4] = v;
  }
  __syncthreads();
  #pragma unroll
  for (int g = 0; g < 2; ++g) {
    const int cl = (q * 2 + g) * 8;
    u16x8 w;
    #pragma unroll
    for (int e = 0; e < 8; ++e) w[e] = f2bf(tile[cl + e][r]);
    *(u16x8*)&xTb[(size_t)(n0 + r) * C_ + c0 + cl] = w;
  }
}

// fghT h-columns [B][N][1024+c] -> hx [B][512][N]  (bf16 32x32 tile transpose)
__global__ __launch_bounds__(256) void transpose_h_k(const u16* __restrict__ fghT, u16* __restrict__ hx) {
  __shared__ u16 tile[32][33];
  const int b = blockIdx.z;
  const int n0 = blockIdx.x * 32, c0 = blockIdx.y * 32;
  const u16* src = fghT + (size_t)b * N_ * 1536;
  u16* dst = hx + (size_t)b * MID_ * N_;
  const int tx = threadIdx.x & 31, ty = threadIdx.x >> 5;
  #pragma unroll
  for (int i = 0; i < 4; ++i)
    tile[ty + i * 8][tx] = src[(size_t)(n0 + ty + i * 8) * 1536 + 1024 + c0 + tx];
  __syncthreads();
  #pragma unroll
  for (int i = 0; i < 4; ++i)
    dst[(size_t)(c0 + ty + i * 8) * N_ + n0 + tx] = tile[tx][ty + i * 8];
}

// ---------------- GEMM: 256x256, BK=64, 2-buf LDS, 4-phase, counted vmcnt, XCD groups --
// OUT[M,N] = A[M,K] * B^T[N,K]; bf16 row-major contiguous-K.
// 1D grid, L2 co-location swizzle: blocks sharing an operand panel get linear ids
// {xcd + 8*(jhi*g + i)} -> same XCD (id%8), same dispatch window -> panel L2-resident.
// SWZ 0: members along x (share A-panel, g=GX); SWZ 1: members along y (share B-panel,
// g=GY); SWZ 2: 3x3 2D groups (share 3 A + 3 B panels). All bijective (group count
// is a multiple of 8 since gz=8).
#define EP_FG 0       // v*scale[col]+bias[col], relu if col<1024, store bf16
#define EP_SCALE16 1  // f2bf(v)
#define EP_FINAL 2    // v+bias[row]+x[row][col], store f32

template<int EPI, int SWZ, int GX, int GY>
__global__ __launch_bounds__(512, 2) void gemm5_kernel(
    const u16* __restrict__ Ag, int lda, long long sA,
    const u16* __restrict__ Bg, int ldb, long long sB,
    void* __restrict__ Cg, int ldc, long long sC, int K,
    const float* __restrict__ ep_scale, const float* __restrict__ ep_bias,
    const float* __restrict__ ep_x, long long sX)
{
  extern __shared__ __align__(16) u16 smem[];
  u16* As = smem;                    // [2][256*64]
  u16* Bs = smem + 2 * 256 * 64;     // [2][256*64]

  // ---- XCD co-location decode ----
  int tx, ty, tz;
  {
    const int L = blockIdx.x;
    const int xcd = L & 7, r = L >> 3;
    if constexpr (SWZ == 0) {
      const int i = r % GX, j = (r / GX) * 8 + xcd;
      tx = i; ty = j % GY; tz = j / GY;
    } else if constexpr (SWZ == 1) {
      const int i = r % GY, j = (r / GY) * 8 + xcd;
      ty = i; tx = j % GX; tz = j / GX;
    } else {
      const int i = r % 9, jg = (r / 9) * 8 + xcd;
      const int bx = jg % (GX / 3), rem = jg / (GX / 3);
      const int by = rem % (GY / 3); tz = rem / (GY / 3);
      tx = bx * 3 + i % 3; ty = by * 3 + i / 3;
    }
  }

  const int tid = threadIdx.x;
  const int lane = tid & 63;
  const int wv = tid >> 6;           // 0..7
  const int b = tz;
  const int m0 = ty * 256;
  const int n0 = tx * 256;
  const int wm = (wv >> 2) * 128;    // 0 / 128
  const int wn = (wv & 3) * 64;      // 0,64,128,192
  const int lr = lane & 15, lg = lane >> 4;

  const u16* Ab = Ag + (size_t)b * sA;
  const u16* Bb = Bg + (size_t)b * sB;
  const int nk = K >> 6;             // K-tiles of 64

  const int srow = lane >> 3;                    // 0..7
  const int sksw = ((lane & 7) ^ srow) * 8;      // pre-swizzled global k-offset

  const int rdsw0 = ((0 + lg) ^ (lr & 7)) * 8;
  const int rdsw1 = ((4 + lg) ^ (lr & 7)) * 8;

  f32x4 acc[8][4];
  #pragma unroll
  for (int i = 0; i < 8; ++i)
    #pragma unroll
    for (int j = 0; j < 4; ++j)
      acc[i][j] = f32x4{0.f, 0.f, 0.f, 0.f};

  auto STAGE_A = [&](int p2, int t) {
    #pragma unroll
    for (int j = 0; j < 4; ++j) {
      const int rb = j * 64 + wv * 8;
      const u16* g = Ab + (size_t)(m0 + rb + srow) * lda + t * 64 + sksw;
      __builtin_amdgcn_global_load_lds((gu32*)g, (su32*)(As + p2 * 16384 + rb * 64), 16, 0, 0);
    }
  };
  auto STAGE_B = [&](int p2, int t) {
    #pragma unroll
    for (int j = 0; j < 4; ++j) {
      const int rb = j * 64 + wv * 8;
      const u16* g = Bb + (size_t)(n0 + rb + srow) * ldb + t * 64 + sksw;
      __builtin_amdgcn_global_load_lds((gu32*)g, (su32*)(Bs + p2 * 16384 + rb * 64), 16, 0, 0);
    }
  };

  STAGE_A(0, 0); STAGE_B(0, 0);
  if (nk > 1) { STAGE_A(1, 1); STAGE_B(1, 1); }

  for (int kt = 0; kt < nk; ++kt) {
    const int p = kt & 1;
    if (kt + 1 < nk) asm volatile("s_waitcnt vmcnt(8)" ::: "memory");
    else             asm volatile("s_waitcnt vmcnt(0)" ::: "memory");
    BAR();

    const u16* Asl = As + p * 16384;
    const u16* Bsl = Bs + p * 16384;
    const bool st = (kt + 2) < nk;
    const int ps = (kt + 2) & 1;

    bf16x8 aV[2][4], bLo[2][2], bHi[2][2];

    // ---- ph0: a(mh0), b(nh0) ----
    #pragma unroll
    for (int ks = 0; ks < 2; ++ks) {
      const int ro = ks ? rdsw1 : rdsw0;
      #pragma unroll
      for (int i = 0; i < 4; ++i)
        aV[ks][i] = *(const bf16x8*)(Asl + (wm + i * 16 + lr) * 64 + ro);
      #pragma unroll
      for (int i = 0; i < 2; ++i)
        bLo[ks][i] = *(const bf16x8*)(Bsl + (wn + i * 16 + lr) * 64 + ro);
    }
    BAR();
    __builtin_amdgcn_s_setprio(1);
    QMFMA(aV, bLo, 0, 0);
    __builtin_amdgcn_s_setprio(0);
    BAR();

    // ---- ph1: b(nh1) ----
    #pragma unroll
    for (int ks = 0; ks < 2; ++ks) {
      const int ro = ks ? rdsw1 : rdsw0;
      #pragma unroll
      for (int i = 0; i < 2; ++i)
        bHi[ks][i] = *(const bf16x8*)(Bsl + (wn + 32 + i * 16 + lr) * 64 + ro);
    }
    BAR();
    __builtin_amdgcn_s_setprio(1);
    QMFMA(aV, bHi, 0, 2);
    __builtin_amdgcn_s_setprio(0);
    BAR();

    // ---- ph2: a(mh1); stage B(kt+2) ----
    #pragma unroll
    for (int ks = 0; ks < 2; ++ks) {
      const int ro = ks ? rdsw1 : rdsw0;
      #pragma unroll
      for (int i = 0; i < 4; ++i)
        aV[ks][i] = *(const bf16x8*)(Asl + (wm + 64 + i * 16 + lr) * 64 + ro);
    }
    if (st) STAGE_B(ps, kt + 2);
    BAR();
    __builtin_amdgcn_s_setprio(1);
    QMFMA(aV, bLo, 4, 0);
    __builtin_amdgcn_s_setprio(0);
    BAR();

    // ---- ph3: stage A(kt+2) ----
    if (st) STAGE_A(ps, kt + 2);
    BAR();
    __builtin_amdgcn_s_setprio(1);
    QMFMA(aV, bHi, 4, 2);
    __builtin_amdgcn_s_setprio(0);
    BAR();
  }

  // epilogue: D row = 4*lg + r, col = lr within each 16x16 fragment
  u16*   C16 = (u16*)Cg + (size_t)b * sC;
  float* C32 = (float*)Cg + (size_t)b * sC;
  const float* xb = (EPI == EP_FINAL) ? (ep_x + (size_t)b * sX) : nullptr;
  #pragma unroll
  for (int mf = 0; mf < 8; ++mf) {
    #pragma unroll
    for (int nf = 0; nf < 4; ++nf) {
      #pragma unroll
      for (int r = 0; r < 4; ++r) {
        int row = m0 + wm + mf * 16 + lg * 4 + r;
        int col = n0 + wn + nf * 16 + lr;
        float v = acc[mf][nf][r];
        if constexpr (EPI == EP_FG) {
          v = v * ep_scale[col] + ep_bias[col];
          if (col < 1024) v = fmaxf(v, 0.f);
          C16[(size_t)row * ldc + col] = f2bf(v);
        } else if constexpr (EPI == EP_SCALE16) {
          C16[(size_t)row * ldc + col] = f2bf(v);
        } else {
          v += ep_bias[row] + xb[(size_t)row * ldc + col];
          C32[(size_t)row * ldc + col] = v;
        }
      }
    }
  }
}

// -------- softmax: read bf16 scores, write f32 attn + bf16 P in place over scores -----
__global__ __launch_bounds__(256) void softmax_k(u16* __restrict__ SP, float* __restrict__ attn) {
  u16* sp = SP + (size_t)blockIdx.x * N_;
  float* ar = attn + (size_t)blockIdx.x * N_;
  const int tid = threadIdx.x;
  u16x8 s8 = *(const u16x8*)&sp[tid * 8];
  u16 st = sp[2048 + tid];
  float w[8], wt = bf2f(st);
  #pragma unroll
  for (int j = 0; j < 8; ++j) w[j] = bf2f(s8[j]);
  float mx = wt;
  #pragma unroll
  for (int j = 0; j < 8; ++j) mx = fmaxf(mx, w[j]);
  #pragma unroll
  for (int o = 32; o; o >>= 1) mx = fmaxf(mx, __shfl_xor(mx, o));
  __shared__ float red[4], red2[4];
  if ((tid & 63) == 0) red[tid >> 6] = mx;
  __syncthreads();
  mx = fmaxf(fmaxf(red[0], red[1]), fmaxf(red[2], red[3]));
  float s = 0.f;
  #pragma unroll
  for (int j = 0; j < 8; ++j) { w[j] = __expf(w[j] - mx); s += w[j]; }
  wt = __expf(wt - mx); s += wt;
  #pragma unroll
  for (int o = 32; o; o >>= 1) s += __shfl_xor(s, o);
  if ((tid & 63) == 0) red2[tid >> 6] = s;
  __syncthreads();
  s = red2[0] + red2[1] + red2[2] + red2[3];
  float inv = 1.0f / s;
  #pragma unroll
  for (int j = 0; j < 8; ++j) w[j] *= inv;
  wt *= inv;
  float4 o0 = {w[0], w[1], w[2], w[3]}, o1 = {w[4], w[5], w[6], w[7]};
  *(float4*)&ar[tid * 8] = o0;
  *(float4*)&ar[tid * 8 + 4] = o1;
  ar[2048 + tid] = wt;
  u16x8 p8;
  #pragma unroll
  for (int j = 0; j < 8; ++j) p8[j] = f2bf(w[j]);
  *(u16x8*)&sp[tid * 8] = p8;
  sp[2048 + tid] = f2bf(wt);
}

// ---------------- launch ----------------
extern "C" void kernel_launch(void* const* d_in, const int* in_sizes, int n_in,
                              void* d_out, int out_size, void* d_ws, size_t ws_size,
                              hipStream_t stream) {
  const float* x    = (const float*)d_in[0];
  const float* f_w  = (const float*)d_in[1];
  const float* f_b  = (const float*)d_in[2];
  const float* f_ga = (const float*)d_in[3];
  const float* f_be = (const float*)d_in[4];
  const float* f_me = (const float*)d_in[5];
  const float* f_va = (const float*)d_in[6];
  const float* g_w  = (const float*)d_in[7];
  const float* g_b  = (const float*)d_in[8];
  const float* g_ga = (const float*)d_in[9];
  const float* g_be = (const float*)d_in[10];
  const float* g_me = (const float*)d_in[11];
  const float* g_va = (const float*)d_in[12];
  const float* h_w  = (const float*)d_in[13];
  const float* h_b  = (const float*)d_in[14];
  const float* v_w  = (const float*)d_in[15];
  const float* v_b  = (const float*)d_in[16];

  float* out0 = (float*)d_out;
  float* attn = out0 + (size_t)B_ * C_ * N_;   // second output region

  // workspace carve (~263 MB)
  char* p = (char*)d_ws;
  u16* xT   = (u16*)p; p += (size_t)B_ * N_ * C_ * 2;       // 75.5 MB
  u16* fghT = (u16*)p; p += (size_t)B_ * N_ * 1536 * 2;     // 56.6 MB
  u16* hx   = (u16*)p; p += (size_t)B_ * MID_ * N_ * 2;     // 18.9 MB
  u16* ZT   = (u16*)p; p += (size_t)B_ * N_ * MID_ * 2;     // 18.9 MB
  u16* Wall = (u16*)p; p += (size_t)1536 * C_ * 2;          // 6.3 MB
  u16* vwb  = (u16*)p; p += (size_t)C_ * MID_ * 2;          // 2.1 MB
  float* sc = (float*)p; p += 1536 * 4;
  float* bi = (float*)p; p += 1536 * 4;
  u16* SP   = (u16*)p; p += (size_t)B_ * N_ * N_ * 2;       // 85 MB (scores bf16 -> P bf16)

  hipFuncSetAttribute((const void*)gemm5_kernel<EP_FG, 0, 6, 9>,      hipFuncAttributeMaxDynamicSharedMemorySize, 131072);
  hipFuncSetAttribute((const void*)gemm5_kernel<EP_SCALE16, 2, 9, 9>, hipFuncAttributeMaxDynamicSharedMemorySize, 131072);
  hipFuncSetAttribute((const void*)gemm5_kernel<EP_SCALE16, 0, 2, 9>, hipFuncAttributeMaxDynamicSharedMemorySize, 131072);
  hipFuncSetAttribute((const void*)gemm5_kernel<EP_FINAL, 1, 9, 8>,   hipFuncAttributeMaxDynamicSharedMemorySize, 131072);

  prep_wall_k<<<(1536 * 2048 + 255) / 256, 256, 0, stream>>>(f_w, g_w, h_w, Wall);
  prep_vw_k<<<(2048 * 512 + 255) / 256, 256, 0, stream>>>(v_w, vwb);
  prep_sb_k<<<6, 256, 0, stream>>>(f_b, f_ga, f_be, f_me, f_va,
                                   g_b, g_ga, g_be, g_me, g_va, h_b, sc, bi);
  transpose_x_k<<<dim3(N_ / 64, C_ / 64, B_), 256, 0, stream>>>(x, xT);

  // G1: fghT[n][c'] = xT[n][:].Wall[c'][:] (M=2304,N=1536,K=2048); share A-panel along x
  gemm5_kernel<EP_FG, 0, 6, 9><<<dim3(6 * 9 * 8), 512, 131072, stream>>>(
      xT, C_, (long long)N_ * C_, Wall, C_, 0,
      fghT, 1536, (long long)N_ * 1536, C_, sc, bi, nullptr, 0);

  // hx[c][n] = fghT[n][1024+c]
  transpose_h_k<<<dim3(N_ / 32, MID_ / 32, B_), 256, 0, stream>>>(fghT, hx);

  // G2: scores bf16 = f.g^T (fscale folded into f) (M=N=2304,K=512); 3x3 XCD groups
  gemm5_kernel<EP_SCALE16, 2, 9, 9><<<dim3(9 * 9 * 8), 512, 131072, stream>>>(
      fghT, 1536, (long long)N_ * 1536, fghT + 512, 1536, (long long)N_ * 1536,
      SP, N_, (long long)N_ * N_, MID_, nullptr, nullptr, nullptr, 0);

  softmax_k<<<B_ * N_, 256, 0, stream>>>(SP, attn);

  // G3: ZT[n][c] = P[n][:].hx[c][:] (M=2304,N=512,K=2304); share A(P)-panel along x
  gemm5_kernel<EP_SCALE16, 0, 2, 9><<<dim3(2 * 9 * 8), 512, 131072, stream>>>(
      SP, N_, (long long)N_ * N_, hx, N_, (long long)MID_ * N_,
      ZT, MID_, (long long)N_ * MID_, N_, nullptr, nullptr, nullptr, 0);

  // G5: out[o][n] = vwb[o][:].ZT[n][:] + v_b[o] + x[o][n] (M=2048,N=2304,K=512); share B along y
  gemm5_kernel<EP_FINAL, 1, 9, 8><<<dim3(9 * 8 * 8), 512, 131072, stream>>>(
      vwb, MID_, 0, ZT, MID_, (long long)N_ * MID_,
      out0, N_, (long long)C_ * N_, MID_, nullptr, v_b, x, (long long)C_ * N_);
}